// Round 3
// baseline (301.009 us; speedup 1.0000x reference)
//
#include <hip/hip_runtime.h>

#define N_ 8192
#define INF_ 512
#define OUTF_ 256
#define KVSPLIT 8
#define BK 32
#define BQ 128
#define NTILES (N_ / KVSPLIT / BK)   // 32

typedef float f32x4 __attribute__((ext_vector_type(4)));
typedef __bf16 bf16x8 __attribute__((ext_vector_type(8)));

__device__ __forceinline__ unsigned short f2bf(float f) {
  union { float f; unsigned u; } v; v.f = f;
  unsigned r = v.u + 0x7fffu + ((v.u >> 16) & 1u);
  return (unsigned short)(r >> 16);
}
__device__ __forceinline__ float bf2f(unsigned short u) {
  union { unsigned u; float f; } v; v.u = ((unsigned)u) << 16;
  return v.f;
}

// ---------------------------------------------------------------------------
// Kernel 0: bit-pack adjacency. 256 MB int32 -> 8 MB bitmask.
// One wave reads 64 consecutive ints, __ballot -> u64.
// ---------------------------------------------------------------------------
__global__ __launch_bounds__(256) void k_pack(
    const int* __restrict__ adj, unsigned long long* __restrict__ adjb)
{
  const int CHUNKS = N_ * (N_ / 64);              // 1M u64 chunks
  int wid = (blockIdx.x * 256 + threadIdx.x) >> 6;
  int lane = threadIdx.x & 63;
  int nw = gridDim.x * 4;                          // waves total
  int per = CHUNKS / nw;                           // chunks per wave
  size_t base = (size_t)wid * per;
#pragma unroll 4
  for (int i = 0; i < per; ++i) {
    size_t ch = base + i;
    int v = adj[ch * 64 + lane];
    unsigned long long m = __ballot(v != 0);
    if (lane == 0) adjb[ch] = m;
  }
}

// ---------------------------------------------------------------------------
// Kernel 1: h = x @ W (f32 accum). Emits h (bf16) and h^T (bf16).
// ---------------------------------------------------------------------------
__global__ __launch_bounds__(256) void k_gemm_h(
    const float* __restrict__ x, const float* __restrict__ W,
    unsigned short* __restrict__ hK, unsigned short* __restrict__ hT)
{
  __shared__ float xT[32][68];
  __shared__ float Wt[32][68];
  int tid = threadIdx.x;
  int tc = tid & 15, tr = tid >> 4;
  int r0 = blockIdx.x * 64;
  int c0 = blockIdx.y * 64;
  float acc[4][4] = {};
#pragma unroll 1
  for (int kt = 0; kt < 16; ++kt) {
    int k0 = kt * 32;
    __syncthreads();
    {
      int row = tid >> 2;
      int kc = (tid & 3) * 8;
      const float* src = x + (size_t)(r0 + row) * INF_ + k0 + kc;
      float4 v0 = *(const float4*)src;
      float4 v1 = *(const float4*)(src + 4);
      xT[kc+0][row] = v0.x; xT[kc+1][row] = v0.y;
      xT[kc+2][row] = v0.z; xT[kc+3][row] = v0.w;
      xT[kc+4][row] = v1.x; xT[kc+5][row] = v1.y;
      xT[kc+6][row] = v1.z; xT[kc+7][row] = v1.w;
    }
    {
      int kr = tid >> 3;
      int cc = (tid & 7) * 8;
      const float* src = W + (size_t)(k0 + kr) * OUTF_ + c0 + cc;
      float4 v0 = *(const float4*)src;
      float4 v1 = *(const float4*)(src + 4);
      *(float4*)&Wt[kr][cc]   = v0;
      *(float4*)&Wt[kr][cc+4] = v1;
    }
    __syncthreads();
#pragma unroll
    for (int k = 0; k < 32; ++k) {
      float av[4], bv[4];
      *(float4*)av = *(const float4*)&xT[k][tr*4];
      *(float4*)bv = *(const float4*)&Wt[k][tc*4];
#pragma unroll
      for (int i = 0; i < 4; ++i)
#pragma unroll
        for (int j = 0; j < 4; ++j)
          acc[i][j] = fmaf(av[i], bv[j], acc[i][j]);
    }
  }
#pragma unroll
  for (int i = 0; i < 4; ++i) {
    int r = r0 + tr*4 + i;
    int c = c0 + tc*4;
    unsigned short hb[4];
#pragma unroll
    for (int j = 0; j < 4; ++j) {
      float h = acc[i][j];
      hb[j] = f2bf(h);
      hT[(size_t)(c + j) * N_ + r] = hb[j];
    }
    *(uint2*)&hK[(size_t)r * OUTF_ + c] = *(uint2*)hb;
  }
}

// ---------------------------------------------------------------------------
// Kernel 2: fused masked attention, fixed-reference softmax (M=0).
// 4 waves x 32 q-rows (BQ=128). KV tile BK=32, single LDS buffer, 2 blk/CU.
// ---------------------------------------------------------------------------
__global__ __launch_bounds__(256, 2) void k_attn(
    const unsigned short* __restrict__ hK, const unsigned short* __restrict__ hT,
    const unsigned* __restrict__ adjb, const float* __restrict__ a,
    unsigned short* __restrict__ Opart, float* __restrict__ lsum)
{
  __shared__ __align__(16) unsigned char smem[16384 + 16384 + 4 * 4352];
  unsigned char* Kl = smem;
  unsigned char* Vl = smem + 16384;

  const int tid = threadIdx.x;
  const int w = tid >> 6, l = tid & 63, g = l >> 4, li = l & 15;
  unsigned char* Pl = smem + 32768 + w * 4352;

  const int qrw = blockIdx.x * BQ + w * 32;
  const int split = blockIdx.y;
  const int j0base = split * (N_ / KVSPLIT);
  const float SCALE = 0.18033688011112042f; // log2(e)/8

  // staging source offsets (elements)
  int offK[4], offV[4];
#pragma unroll
  for (int p = 0; p < 4; ++p) {
    int ch = tid + p * 256;
    int row = ch >> 5, c16 = ch & 31;
    offK[p] = row * OUTF_ + ((c16 ^ (row & 7)) * 8);
    int d = ch >> 2, c = ch & 3;
    offV[p] = d * N_ + ((c ^ (d & 3)) * 8);
  }
  // LDS read offsets
  int cxor[8];
#pragma unroll
  for (int kt = 0; kt < 8; ++kt) cxor[kt] = ((kt*4 + g) ^ (li & 7)) * 16;
  const int kbase = li * 512;
  const int voff  = li * 64 + ((g ^ (li & 3)) * 16);

  // adjacency bitmask row bases (dword indices)
  const int rowb0 = (qrw + 4*g) * (N_/32) + split * 32;
  const int rowb1 = rowb0 + 16 * (N_/32);

  // Q = (h * a) fragments, built from hK + a
  bf16x8 Qf[2][8];
#pragma unroll
  for (int rg = 0; rg < 2; ++rg) {
    const unsigned short* hp = hK + (size_t)(qrw + rg*16 + li) * OUTF_;
#pragma unroll
    for (int kt = 0; kt < 8; ++kt) {
      bf16x8 hv = *(const bf16x8*)(hp + kt*32 + g*8);
      const float* ap = a + kt*32 + g*8;
      float4 a0 = *(const float4*)ap;
      float4 a1 = *(const float4*)(ap + 4);
      bf16x8 q;
      q[0] = (__bf16)((float)hv[0] * a0.x);
      q[1] = (__bf16)((float)hv[1] * a0.y);
      q[2] = (__bf16)((float)hv[2] * a0.z);
      q[3] = (__bf16)((float)hv[3] * a0.w);
      q[4] = (__bf16)((float)hv[4] * a1.x);
      q[5] = (__bf16)((float)hv[5] * a1.y);
      q[6] = (__bf16)((float)hv[6] * a1.z);
      q[7] = (__bf16)((float)hv[7] * a1.w);
      Qf[rg][kt] = q;
    }
  }

  f32x4 O[2][16];
  const f32x4 z4 = {0.f, 0.f, 0.f, 0.f};
#pragma unroll
  for (int rg = 0; rg < 2; ++rg)
#pragma unroll
    for (int dt = 0; dt < 16; ++dt) O[rg][dt] = z4;
  float lp[2][4] = {};

#pragma unroll 1
  for (int t = 0; t < NTILES; ++t) {
    const int j0 = j0base + t * BK;
    __syncthreads();     // previous tile fully consumed
    const unsigned short* hKt = hK + (size_t)j0 * OUTF_;
    const unsigned short* hTt = hT + j0;
#pragma unroll
    for (int p = 0; p < 4; ++p)
      __builtin_amdgcn_global_load_lds(
        (const __attribute__((address_space(1))) void*)(hKt + offK[p]),
        (__attribute__((address_space(3))) void*)(Kl + (p*256 + w*64)*16), 16, 0, 0);
#pragma unroll
    for (int p = 0; p < 4; ++p)
      __builtin_amdgcn_global_load_lds(
        (const __attribute__((address_space(1))) void*)(hTt + offV[p]),
        (__attribute__((address_space(3))) void*)(Vl + (p*256 + w*64)*16), 16, 0, 0);
    unsigned dw0[4], dw1[4];
#pragma unroll
    for (int s = 0; s < 4; ++s) {
      dw0[s] = adjb[rowb0 + s*(N_/32) + t];
      dw1[s] = adjb[rowb1 + s*(N_/32) + t];
    }
    __syncthreads();     // staging complete (vmcnt drained by barrier)

    // ---- S = Q K^T  (two 16-row groups share each kf)
    f32x4 S0[2], S1[2];
#pragma unroll
    for (int jt = 0; jt < 2; ++jt) { S0[jt] = z4; S1[jt] = z4; }
#pragma unroll
    for (int jt = 0; jt < 2; ++jt) {
#pragma unroll
      for (int kt = 0; kt < 8; ++kt) {
        bf16x8 kf = *(const bf16x8*)(Kl + kbase + jt*8192 + cxor[kt]);
        S0[jt] = __builtin_amdgcn_mfma_f32_16x16x32_bf16(Qf[0][kt], kf, S0[jt], 0, 0, 0);
        S1[jt] = __builtin_amdgcn_mfma_f32_16x16x32_bf16(Qf[1][kt], kf, S1[jt], 0, 0, 0);
      }
    }
    // ---- fixed-reference masked exp, accumulate l per-lane, P -> LDS
#pragma unroll
    for (int s = 0; s < 4; ++s) {
      unsigned char* p0 = Pl + (unsigned)(4*g + s) * 136 + (unsigned)li * 2;
      unsigned char* p1 = p0 + 16 * 136;
#pragma unroll
      for (int jt = 0; jt < 2; ++jt) {
        int sh = jt*16 + li;
        float e0 = exp2f(S0[jt][s] * SCALE);
        float e1 = exp2f(S1[jt][s] * SCALE);
        float v0 = ((dw0[s] >> sh) & 1u) ? e0 : 0.f;
        float v1 = ((dw1[s] >> sh) & 1u) ? e1 : 0.f;
        lp[0][s] += v0;
        lp[1][s] += v1;
        *(__bf16*)(p0 + jt*32) = (__bf16)v0;
        *(__bf16*)(p1 + jt*32) = (__bf16)v1;
      }
    }
    asm volatile("s_waitcnt lgkmcnt(0)" ::: "memory");
    __builtin_amdgcn_sched_barrier(0);
    // ---- O += P V  (one K=32 step per tile)
    bf16x8 pf0 = *(const bf16x8*)(Pl + (unsigned)li * 136 + g*16);
    bf16x8 pf1 = *(const bf16x8*)(Pl + (unsigned)(16 + li) * 136 + g*16);
#pragma unroll
    for (int dt = 0; dt < 16; ++dt) {
      bf16x8 vf = *(const bf16x8*)(Vl + voff + dt*1024);
      O[0][dt] = __builtin_amdgcn_mfma_f32_16x16x32_bf16(pf0, vf, O[0][dt], 0, 0, 0);
      O[1][dt] = __builtin_amdgcn_mfma_f32_16x16x32_bf16(pf1, vf, O[1][dt], 0, 0, 0);
    }
  }

  // ---- epilogue: l (reduce over li) and O (bf16 partials)
#pragma unroll
  for (int rg = 0; rg < 2; ++rg)
#pragma unroll
    for (int s = 0; s < 4; ++s) {
      float v = lp[rg][s];
#pragma unroll
      for (int off = 1; off < 16; off <<= 1) v += __shfl_xor(v, off);
      if (li == 0)
        lsum[(size_t)split * N_ + qrw + rg*16 + 4*g + s] = v;
    }
  const size_t ob = (size_t)split * N_ * OUTF_;
#pragma unroll
  for (int rg = 0; rg < 2; ++rg)
#pragma unroll
    for (int s = 0; s < 4; ++s) {
      unsigned short* op = Opart + ob + (size_t)(qrw + rg*16 + 4*g + s) * OUTF_ + li;
#pragma unroll
      for (int dt = 0; dt < 16; ++dt)
        op[dt*16] = f2bf(O[rg][dt][s]);
    }
}

// ---------------------------------------------------------------------------
// Kernel 3: combine splits (plain sums), normalize, ELU.
// ---------------------------------------------------------------------------
__global__ __launch_bounds__(256) void k_combine(
    const unsigned short* __restrict__ Opart, const float* __restrict__ lsum,
    float* __restrict__ out)
{
  int idx = blockIdx.x * 256 + threadIdx.x;   // N*64 threads
  int row = idx >> 6;
  int c = (idx & 63) * 4;
  float L = 0.f, a0 = 0.f, a1 = 0.f, a2 = 0.f, a3 = 0.f;
#pragma unroll
  for (int s = 0; s < KVSPLIT; ++s) {
    L += lsum[(size_t)s * N_ + row];
    uint2 o = *(const uint2*)(Opart + ((size_t)s * N_ + row) * OUTF_ + c);
    a0 += bf2f((unsigned short)(o.x & 0xffff));
    a1 += bf2f((unsigned short)(o.x >> 16));
    a2 += bf2f((unsigned short)(o.y & 0xffff));
    a3 += bf2f((unsigned short)(o.y >> 16));
  }
  float inv = 1.f / L;
  float r0 = a0 * inv, r1 = a1 * inv, r2 = a2 * inv, r3 = a3 * inv;
  float4 r;
  r.x = r0 > 0.f ? r0 : expm1f(r0);
  r.y = r1 > 0.f ? r1 : expm1f(r1);
  r.z = r2 > 0.f ? r2 : expm1f(r2);
  r.w = r3 > 0.f ? r3 : expm1f(r3);
  *(float4*)(out + (size_t)row * OUTF_ + c) = r;
}

// ---------------------------------------------------------------------------
extern "C" void kernel_launch(void* const* d_in, const int* in_sizes, int n_in,
                              void* d_out, int out_size, void* d_ws, size_t ws_size,
                              hipStream_t stream) {
  const float* x  = (const float*)d_in[0];
  const int* adj  = (const int*)d_in[1];
  const float* W  = (const float*)d_in[2];
  const float* a  = (const float*)d_in[3];
  float* out = (float*)d_out;
  char* ws = (char*)d_ws;

  unsigned short* hK = (unsigned short*)(ws);                        // 4 MB
  unsigned short* hT = (unsigned short*)(ws + (size_t)4*1024*1024);  // 4 MB
  unsigned long long* adjb = (unsigned long long*)(ws + (size_t)8*1024*1024);  // 8 MB
  unsigned short* Opart = (unsigned short*)(ws + (size_t)16*1024*1024);        // 32 MB (bf16)
  float* lsum = (float*)(ws + (size_t)48*1024*1024);                 // 256 KB

  k_pack<<<2048, 256, 0, stream>>>(adj, adjb);
  dim3 g1(N_/64, OUTF_/64);
  k_gemm_h<<<g1, 256, 0, stream>>>(x, W, hK, hT);
  dim3 g2(N_/BQ, KVSPLIT);
  k_attn<<<g2, 256, 0, stream>>>(hK, hT, (const unsigned*)adjb, a, Opart, lsum);
  k_combine<<<(N_*64)/256, 256, 0, stream>>>(Opart, lsum, out);
}

// Round 4
// 196.839 us; speedup vs baseline: 1.5292x; 1.5292x over previous
//
#include <hip/hip_runtime.h>

#define N_ 8192
#define INF_ 512
#define OUTF_ 256
#define KVSPLIT 8
#define BK 32
#define BQ 128
#define NTILES (N_ / KVSPLIT / BK)   // 32

typedef float f32x4 __attribute__((ext_vector_type(4)));
typedef __bf16 bf16x8 __attribute__((ext_vector_type(8)));

__device__ __forceinline__ unsigned short f2bf(float f) {
  union { float f; unsigned u; } v; v.f = f;
  unsigned r = v.u + 0x7fffu + ((v.u >> 16) & 1u);
  return (unsigned short)(r >> 16);
}
__device__ __forceinline__ float bf2f(unsigned short u) {
  union { unsigned u; float f; } v; v.u = ((unsigned)u) << 16;
  return v.f;
}

// ---------------------------------------------------------------------------
// Kernel 0: prep. x -> xhi+xlo (bf16 split), W -> WT (bf16, [col][k]).
// ---------------------------------------------------------------------------
__global__ __launch_bounds__(256) void k_prep(
    const float* __restrict__ x, const float* __restrict__ W,
    unsigned short* __restrict__ xhi, unsigned short* __restrict__ xlo,
    unsigned short* __restrict__ WT)
{
  int idx = blockIdx.x * 256 + threadIdx.x;     // 1M threads, one float4 each
  float4 v = ((const float4*)x)[idx];
  float f[4] = {v.x, v.y, v.z, v.w};
  unsigned short h[4], lo[4];
#pragma unroll
  for (int j = 0; j < 4; ++j) {
    h[j] = f2bf(f[j]);
    lo[j] = f2bf(f[j] - bf2f(h[j]));
  }
  *(uint2*)&xhi[idx * 4] = *(uint2*)h;
  *(uint2*)&xlo[idx * 4] = *(uint2*)lo;
  if (idx < INF_ * OUTF_) {
    int c = idx & (OUTF_ - 1);
    int k = idx >> 8;
    WT[c * INF_ + k] = f2bf(W[k * OUTF_ + c]);
  }
}

// ---------------------------------------------------------------------------
// Kernel 1: h = x @ W via bf16 MFMA (hi/lo split for x). No LDS.
// Emits h (bf16 [N][256]) and h^T (bf16 [256][N]).
// ---------------------------------------------------------------------------
__global__ __launch_bounds__(256) void k_gemm_h(
    const unsigned short* __restrict__ xhi, const unsigned short* __restrict__ xlo,
    const unsigned short* __restrict__ WT,
    unsigned short* __restrict__ hK, unsigned short* __restrict__ hT)
{
  const int tid = threadIdx.x;
  const int w = tid >> 6, l = tid & 63, g = l >> 4, li = l & 15;
  const int r0 = blockIdx.x * 64 + w * 16;
  const int c0 = blockIdx.y * 64;

  f32x4 acc[4];
  const f32x4 z4 = {0.f, 0.f, 0.f, 0.f};
#pragma unroll
  for (int n = 0; n < 4; ++n) acc[n] = z4;

  const unsigned short* xh = xhi + (size_t)(r0 + li) * INF_ + g * 8;
  const unsigned short* xl = xlo + (size_t)(r0 + li) * INF_ + g * 8;
  const unsigned short* wt = WT + (size_t)(c0 + li) * INF_ + g * 8;

#pragma unroll 4
  for (int kc = 0; kc < 16; ++kc) {
    bf16x8 Ah = *(const bf16x8*)(xh + kc * 32);
    bf16x8 Al = *(const bf16x8*)(xl + kc * 32);
#pragma unroll
    for (int n = 0; n < 4; ++n) {
      bf16x8 Bn = *(const bf16x8*)(wt + (size_t)n * 16 * INF_ + kc * 32);
      acc[n] = __builtin_amdgcn_mfma_f32_16x16x32_bf16(Ah, Bn, acc[n], 0, 0, 0);
      acc[n] = __builtin_amdgcn_mfma_f32_16x16x32_bf16(Al, Bn, acc[n], 0, 0, 0);
    }
  }
#pragma unroll
  for (int n = 0; n < 4; ++n)
#pragma unroll
    for (int s = 0; s < 4; ++s) {
      unsigned short b = f2bf(acc[n][s]);
      int row = r0 + 4 * g + s;
      int col = c0 + n * 16 + li;
      hK[(size_t)row * OUTF_ + col] = b;
      hT[(size_t)col * N_ + row] = b;
    }
}

// ---------------------------------------------------------------------------
// Kernel 2: fused masked attention. Swapped QK (St = K·Q^T), in-register P,
// double-buffered K/V LDS, adj streamed directly as int4. Fixed-ref softmax.
// 4 waves x 32 q-rows. BK=32. 64KB LDS -> 2 blocks/CU.
// ---------------------------------------------------------------------------
__global__ __launch_bounds__(256, 2) void k_attn(
    const unsigned short* __restrict__ hK, const unsigned short* __restrict__ hT,
    const int* __restrict__ adj, const float* __restrict__ a,
    unsigned short* __restrict__ Opart, float* __restrict__ lsum)
{
  __shared__ __align__(16) unsigned char smem[65536];
  unsigned char* KA = smem;
  unsigned char* VA = smem + 16384;
  unsigned char* KB = smem + 32768;
  unsigned char* VB = smem + 49152;

  const int tid = threadIdx.x;
  const int w = tid >> 6, l = tid & 63, g = l >> 4, li = l & 15;
  const int bid = blockIdx.x;
  const int split = bid & 7;          // XCD-aligned: all blocks on an XCD share split
  const int qb = bid >> 3;
  const int qrw = qb * BQ + w * 32;
  const int jb = split * (N_ / KVSPLIT);
  const float SCALE = 0.18033688011112042f;  // log2(e)/8

  // staging offsets
  int offK[4], offV[4];
#pragma unroll
  for (int p = 0; p < 4; ++p) {
    int ch = tid + p * 256;
    int rK = ch >> 5, cK = ch & 31;
    offK[p] = rK * OUTF_ + ((cK ^ (rK & 7)) * 8);
    int dV = ch >> 2, cV = ch & 3;
    offV[p] = dV * N_ + ((cV ^ ((dV ^ (dV >> 2)) & 3)) * 8);
  }
  int cxor[8];
#pragma unroll
  for (int kt = 0; kt < 8; ++kt) cxor[kt] = ((kt * 4 + g) ^ (li & 7)) * 16;
  const int kbase = li * 512;
  const int voff = li * 64 + ((g ^ ((li ^ (li >> 2)) & 3)) * 16);

  // adj row bases (lane-private rows!)
  const int* adjr0 = adj + (size_t)(qrw + li) * N_ + jb + 4 * g;
  const int* adjr1 = adjr0 + (size_t)16 * N_;

  // Q fragments: q = h * a, built from hK
  bf16x8 Qf[2][8];
#pragma unroll
  for (int rg = 0; rg < 2; ++rg) {
    const unsigned short* hp = hK + (size_t)(qrw + rg * 16 + li) * OUTF_;
#pragma unroll
    for (int kt = 0; kt < 8; ++kt) {
      bf16x8 hv = *(const bf16x8*)(hp + kt * 32 + g * 8);
      const float* ap = a + kt * 32 + g * 8;
      float4 a0 = *(const float4*)ap;
      float4 a1 = *(const float4*)(ap + 4);
      bf16x8 q;
      q[0] = (__bf16)((float)hv[0] * a0.x);
      q[1] = (__bf16)((float)hv[1] * a0.y);
      q[2] = (__bf16)((float)hv[2] * a0.z);
      q[3] = (__bf16)((float)hv[3] * a0.w);
      q[4] = (__bf16)((float)hv[4] * a1.x);
      q[5] = (__bf16)((float)hv[5] * a1.y);
      q[6] = (__bf16)((float)hv[6] * a1.z);
      q[7] = (__bf16)((float)hv[7] * a1.w);
      Qf[rg][kt] = q;
    }
  }

  f32x4 O[2][16];
  const f32x4 z4 = {0.f, 0.f, 0.f, 0.f};
#pragma unroll
  for (int rg = 0; rg < 2; ++rg)
#pragma unroll
    for (int dt = 0; dt < 16; ++dt) O[rg][dt] = z4;
  float lp[2] = {0.f, 0.f};

  const bool lo32 = (l < 32);
  const bool geven = ((l & 16) == 0);

#define STAGE(tt, Kd, Vd) do { \
    const unsigned short* _hk = hK + (size_t)(jb + (tt) * BK) * OUTF_; \
    const unsigned short* _ht = hT + (jb + (tt) * BK); \
    _Pragma("unroll") \
    for (int p = 0; p < 4; ++p) \
      __builtin_amdgcn_global_load_lds( \
        (const __attribute__((address_space(1))) void*)(_hk + offK[p]), \
        (__attribute__((address_space(3))) void*)((Kd) + (p * 256 + w * 64) * 16), 16, 0, 0); \
    _Pragma("unroll") \
    for (int p = 0; p < 4; ++p) \
      __builtin_amdgcn_global_load_lds( \
        (const __attribute__((address_space(1))) void*)(_ht + offV[p]), \
        (__attribute__((address_space(3))) void*)((Vd) + (p * 256 + w * 64) * 16), 16, 0, 0); \
  } while (0)

  STAGE(0, KA, VA);
  __syncthreads();

#pragma unroll 1
  for (int t = 0; t < NTILES; ++t) {
    const unsigned char* Kc = (t & 1) ? KB : KA;
    const unsigned char* Vc = (t & 1) ? VB : VA;
    unsigned char* Kn = (t & 1) ? KA : KB;
    unsigned char* Vn = (t & 1) ? VA : VB;
    if (t < NTILES - 1) STAGE(t + 1, Kn, Vn);

    // adj for this tile (int4 per (rg, jt))
    int4 ad[2][2];
#pragma unroll
    for (int jt = 0; jt < 2; ++jt) {
      ad[0][jt] = *(const int4*)(adjr0 + t * 32 + jt * 16);
      ad[1][jt] = *(const int4*)(adjr1 + t * 32 + jt * 16);
    }

    // ---- St[rg][jt] = K·Q^T  (row = kcol, col = q-row)
    f32x4 St[2][2];
#pragma unroll
    for (int jt = 0; jt < 2; ++jt) { St[0][jt] = z4; St[1][jt] = z4; }
    __builtin_amdgcn_s_setprio(1);
#pragma unroll
    for (int jt = 0; jt < 2; ++jt)
#pragma unroll
      for (int kt = 0; kt < 8; ++kt) {
        bf16x8 kf = *(const bf16x8*)(Kc + kbase + jt * 8192 + cxor[kt]);
        St[0][jt] = __builtin_amdgcn_mfma_f32_16x16x32_bf16(kf, Qf[0][kt], St[0][jt], 0, 0, 0);
        St[1][jt] = __builtin_amdgcn_mfma_f32_16x16x32_bf16(kf, Qf[1][kt], St[1][jt], 0, 0, 0);
      }
    __builtin_amdgcn_s_setprio(0);

    // ---- masked exp (fixed reference), pack to bf16 pairs
    unsigned pkA[2][2], pkB[2][2];
#pragma unroll
    for (int rg = 0; rg < 2; ++rg)
#pragma unroll
      for (int jt = 0; jt < 2; ++jt) {
        float e0 = exp2f(St[rg][jt][0] * SCALE);
        float e1 = exp2f(St[rg][jt][1] * SCALE);
        float e2 = exp2f(St[rg][jt][2] * SCALE);
        float e3 = exp2f(St[rg][jt][3] * SCALE);
        int4 m = ad[rg][jt];
        float v0 = m.x ? e0 : 0.f;
        float v1 = m.y ? e1 : 0.f;
        float v2 = m.z ? e2 : 0.f;
        float v3 = m.w ? e3 : 0.f;
        lp[rg] += (v0 + v1) + (v2 + v3);
        unsigned pA, pB;
        asm("v_cvt_pk_bf16_f32 %0, %1, %2" : "=v"(pA) : "v"(v0), "v"(v1));
        asm("v_cvt_pk_bf16_f32 %0, %1, %2" : "=v"(pB) : "v"(v2), "v"(v3));
        pkA[rg][jt] = pA;
        pkB[rg][jt] = pB;
      }

    // ---- cross-lane exchange: build A-fragment P[q=li][k=8g..8g+7]
    bf16x8 Pf[2];
#pragma unroll
    for (int rg = 0; rg < 2; ++rg) {
      unsigned A0 = pkA[rg][0], A1 = pkA[rg][1];
      unsigned B0 = pkB[rg][0], B1 = pkB[rg][1];
      unsigned sA0 = __shfl_xor(A0, 32), sA1 = __shfl_xor(A1, 32);
      unsigned sB0 = __shfl_xor(B0, 32), sB1 = __shfl_xor(B1, 32);
      unsigned UpA = lo32 ? A0 : sA1, VpA = lo32 ? sA0 : A1;
      unsigned UpB = lo32 ? B0 : sB1, VpB = lo32 ? sB0 : B1;
      unsigned xUA = __shfl_xor(UpA, 16), xVA = __shfl_xor(VpA, 16);
      unsigned xUB = __shfl_xor(UpB, 16), xVB = __shfl_xor(VpB, 16);
      union { unsigned u[4]; bf16x8 v; } pu;
      pu.u[0] = geven ? UpA : xVA;
      pu.u[1] = geven ? UpB : xVB;
      pu.u[2] = geven ? xUA : VpA;
      pu.u[3] = geven ? xUB : VpB;
      Pf[rg] = pu.v;
    }

    // ---- O += P V
    __builtin_amdgcn_s_setprio(1);
#pragma unroll
    for (int dt = 0; dt < 16; ++dt) {
      bf16x8 vf = *(const bf16x8*)(Vc + voff + dt * 1024);
      O[0][dt] = __builtin_amdgcn_mfma_f32_16x16x32_bf16(Pf[0], vf, O[0][dt], 0, 0, 0);
      O[1][dt] = __builtin_amdgcn_mfma_f32_16x16x32_bf16(Pf[1], vf, O[1][dt], 0, 0, 0);
    }
    __builtin_amdgcn_s_setprio(0);

    __syncthreads();
  }
#undef STAGE

  // ---- epilogue
#pragma unroll
  for (int rg = 0; rg < 2; ++rg) {
    float v = lp[rg];
    v += __shfl_xor(v, 16);
    v += __shfl_xor(v, 32);
    if (l < 16)
      lsum[(size_t)split * N_ + qrw + rg * 16 + li] = v;
  }
  const size_t ob = (size_t)split * N_ * OUTF_;
#pragma unroll
  for (int rg = 0; rg < 2; ++rg)
#pragma unroll
    for (int s = 0; s < 4; ++s) {
      unsigned short* op = Opart + ob + (size_t)(qrw + rg * 16 + 4 * g + s) * OUTF_ + li;
#pragma unroll
      for (int dt = 0; dt < 16; ++dt)
        op[dt * 16] = f2bf(O[rg][dt][s]);
    }
}

// ---------------------------------------------------------------------------
// Kernel 3: combine splits (plain sums), normalize, ELU.
// ---------------------------------------------------------------------------
__global__ __launch_bounds__(256) void k_combine(
    const unsigned short* __restrict__ Opart, const float* __restrict__ lsum,
    float* __restrict__ out)
{
  int idx = blockIdx.x * 256 + threadIdx.x;   // N*64 threads
  int row = idx >> 6;
  int c = (idx & 63) * 4;
  float L = 0.f, a0 = 0.f, a1 = 0.f, a2 = 0.f, a3 = 0.f;
#pragma unroll
  for (int s = 0; s < KVSPLIT; ++s) {
    L += lsum[(size_t)s * N_ + row];
    uint2 o = *(const uint2*)(Opart + ((size_t)s * N_ + row) * OUTF_ + c);
    a0 += bf2f((unsigned short)(o.x & 0xffff));
    a1 += bf2f((unsigned short)(o.x >> 16));
    a2 += bf2f((unsigned short)(o.y & 0xffff));
    a3 += bf2f((unsigned short)(o.y >> 16));
  }
  float inv = 1.f / L;
  float r0 = a0 * inv, r1 = a1 * inv, r2 = a2 * inv, r3 = a3 * inv;
  float4 r;
  r.x = r0 > 0.f ? r0 : expm1f(r0);
  r.y = r1 > 0.f ? r1 : expm1f(r1);
  r.z = r2 > 0.f ? r2 : expm1f(r2);
  r.w = r3 > 0.f ? r3 : expm1f(r3);
  *(float4*)(out + (size_t)row * OUTF_ + c) = r;
}

// ---------------------------------------------------------------------------
extern "C" void kernel_launch(void* const* d_in, const int* in_sizes, int n_in,
                              void* d_out, int out_size, void* d_ws, size_t ws_size,
                              hipStream_t stream) {
  const float* x  = (const float*)d_in[0];
  const int* adj  = (const int*)d_in[1];
  const float* W  = (const float*)d_in[2];
  const float* a  = (const float*)d_in[3];
  float* out = (float*)d_out;
  char* ws = (char*)d_ws;

  unsigned short* hK = (unsigned short*)(ws);                             // 0..4MB
  unsigned short* hT = (unsigned short*)(ws + (size_t)4 * 1024 * 1024);   // 4..8MB
  unsigned short* WT = (unsigned short*)(ws + (size_t)8 * 1024 * 1024);   // 8..9MB
  float* lsum = (float*)(ws + (size_t)9 * 1024 * 1024);                   // 9..10MB
  unsigned short* Opart = (unsigned short*)(ws + (size_t)10 * 1024 * 1024); // 10..42MB
  // xhi/xlo alias the Opart region (dead once k_gemm_h finishes)
  unsigned short* xhi = (unsigned short*)(ws + (size_t)10 * 1024 * 1024);
  unsigned short* xlo = (unsigned short*)(ws + (size_t)18 * 1024 * 1024);

  k_prep<<<(N_ * INF_ / 4) / 256, 256, 0, stream>>>(x, W, xhi, xlo, WT);
  dim3 g1(N_ / 64, OUTF_ / 64);
  k_gemm_h<<<g1, 256, 0, stream>>>(xhi, xlo, WT, hK, hT);
  k_attn<<<(N_ / BQ) * KVSPLIT, 256, 0, stream>>>(hK, hT, adj, a, Opart, lsum);
  k_combine<<<(N_ * 64) / 256, 256, 0, stream>>>(Opart, lsum, out);
}